// Round 1
// baseline (307.174 us; speedup 1.0000x reference)
//
#include <hip/hip_runtime.h>

// Problem constants
#define B_SZ  4
#define C_IN  256
#define N_POS 4096     // H*W = 64*64
#define NH    2
#define HC    64       // hidden per head

typedef __attribute__((ext_vector_type(8))) __bf16 bf16x8;
typedef __attribute__((ext_vector_type(4))) float  f32x4;
typedef unsigned short u16;

__device__ __forceinline__ u16 f2bf(float f) {
  unsigned u = __float_as_uint(f);
  u = u + 0x7FFF + ((u >> 16) & 1);   // round-nearest-even
  return (u16)(u >> 16);
}

// ---------------------------------------------------------------------------
// Kernel 0a: x [B][C][N] fp32  ->  x_t [B][N][C] bf16  (transposed cast)
// ---------------------------------------------------------------------------
__global__ __launch_bounds__(256) void k_prep_x(const float* __restrict__ x,
                                                u16* __restrict__ xt) {
  __shared__ float tile[32][33];
  int b = blockIdx.z, c0 = blockIdx.y * 32, n0 = blockIdx.x * 32;
  int tx = threadIdx.x, ty = threadIdx.y;   // (32, 8)
  const float* src = x + ((size_t)b * C_IN + c0) * N_POS + n0;
#pragma unroll
  for (int i = 0; i < 4; i++) tile[ty + 8*i][tx] = src[(size_t)(ty + 8*i) * N_POS + tx];
  __syncthreads();
  u16* dst = xt + ((size_t)b * N_POS + n0) * C_IN + c0;
#pragma unroll
  for (int i = 0; i < 4; i++) dst[(size_t)(ty + 8*i) * C_IN + tx] = f2bf(tile[tx][ty + 8*i]);
}

// ---------------------------------------------------------------------------
// Kernel 0b: cast embed_w -> wbf [384][256] bf16 ; transpose out_w -> w2t [256][128] bf16
// ---------------------------------------------------------------------------
__global__ __launch_bounds__(256) void k_prep_w(const float* __restrict__ ew,
                                                const float* __restrict__ ow,
                                                u16* __restrict__ wbf,
                                                u16* __restrict__ w2t) {
  int i = blockIdx.x * 256 + threadIdx.x;
  if (i < 384 * 256) wbf[i] = f2bf(ew[i]);
  if (i < 128 * 256) {
    int d = i >> 8, c = i & 255;              // out_w[d][c]
    w2t[c * 128 + d] = f2bf(ow[i]);
  }
}

// ---------------------------------------------------------------------------
// Kernel 1: QKV projection.  qkv[m][n] = sum_c W[m][c] * x[c][n] + bias
//   D-tile: rows = n (from x_t), cols = m (from W).
//   q -> Qt [bh][N][64] (n-major, pre-scaled by 1/16)
//   k -> Kt [bh][N][64] (n-major)
//   v -> Vc [bh][64][N] (c-major)
// ---------------------------------------------------------------------------
__global__ __launch_bounds__(256) void k_qkv(const u16* __restrict__ xt,
                                             const u16* __restrict__ wbf,
                                             const float* __restrict__ eb,
                                             u16* __restrict__ Qt,
                                             u16* __restrict__ Kt,
                                             u16* __restrict__ Vc) {
  int b = blockIdx.z;          // 4
  int mt = blockIdx.y;         // 6  (64-wide m tiles; 192 per head = 3 tiles)
  int nt = blockIdx.x;         // 64 (64-wide n tiles)
  int w = threadIdx.x >> 6, l = threadIdx.x & 63;
  int lr = l & 15, lg = l >> 4;
  int h = mt / 3, type = mt % 3;

  const u16* arow = xt + ((size_t)b * N_POS + nt*64 + w*16 + lr) * C_IN + lg*8;
  const u16* brow = wbf + ((size_t)(mt*64) + lr) * C_IN + lg*8;

  f32x4 acc[4] = {};
#pragma unroll
  for (int kk = 0; kk < 8; kk++) {
    bf16x8 a = *(const bf16x8*)(arow + kk*32);
#pragma unroll
    for (int mf = 0; mf < 4; mf++) {
      bf16x8 bf = *(const bf16x8*)(brow + (size_t)mf*16*C_IN + kk*32);
      acc[mf] = __builtin_amdgcn_mfma_f32_16x16x32_bf16(a, bf, acc[mf], 0, 0, 0);
    }
  }

  int bh = b * NH + h;
  int n0 = nt*64 + w*16 + lg*4;   // 4 consecutive rows (regs)
#pragma unroll
  for (int mf = 0; mf < 4; mf++) {
    int cl = mf*16 + lr;                        // channel within head [0,64)
    float bias = eb[h*192 + type*64 + cl];
    if (type == 0) {
      u16* q = Qt + (size_t)bh * N_POS * HC;
#pragma unroll
      for (int r = 0; r < 4; r++) q[(size_t)(n0+r)*HC + cl] = f2bf((acc[mf][r] + bias) * 0.0625f);
    } else if (type == 1) {
      u16* kd = Kt + (size_t)bh * N_POS * HC;
#pragma unroll
      for (int r = 0; r < 4; r++) kd[(size_t)(n0+r)*HC + cl] = f2bf(acc[mf][r] + bias);
    } else {
      u16* vd = Vc + ((size_t)bh * HC + cl) * N_POS;
#pragma unroll
      for (int r = 0; r < 4; r++) vd[n0 + r] = f2bf(acc[mf][r] + bias);
    }
  }
}

// ---------------------------------------------------------------------------
// Kernel 2: flash attention per (b,h).  Q tile 64 rows/block, 16 rows/wave.
//   S = Q_t . K_t^T  (k = c, 2 MFMA steps);  online softmax;  O += P . V
// ---------------------------------------------------------------------------
#define KVT 64
__global__ __launch_bounds__(256) void k_attn(const u16* __restrict__ Qt,
                                              const u16* __restrict__ Kt,
                                              const u16* __restrict__ Vc,
                                              u16* __restrict__ Ot) {
  int bh = blockIdx.y;            // 8
  int mt = blockIdx.x;            // 64 tiles of 64 query rows
  int b = bh >> 1, h = bh & 1;
  int w = threadIdx.x >> 6, l = threadIdx.x & 63;
  int lr = l & 15, lg = l >> 4;

  __shared__ u16 plds[4][16][80];   // per-wave P tile, padded stride 80 (160B)

  const u16* qbase = Qt + ((size_t)bh * N_POS + mt*64 + w*16 + lr) * HC + lg*8;
  bf16x8 qf0 = *(const bf16x8*)(qbase);
  bf16x8 qf1 = *(const bf16x8*)(qbase + 32);

  const u16* kbase = Kt + (size_t)bh * N_POS * HC;
  const u16* vbase = Vc + (size_t)bh * HC * N_POS;

  f32x4 o[4] = {};
  float rm[4], rs[4];
#pragma unroll
  for (int r = 0; r < 4; r++) { rm[r] = -1e30f; rs[r] = 0.f; }

  for (int nt = 0; nt < N_POS / KVT; nt++) {
    // ---- S = Q K^T  (16 m x 64 n per wave) ----
    f32x4 s[4] = {};
#pragma unroll
    for (int nf = 0; nf < 4; nf++) {
      const u16* kp = kbase + (size_t)(nt*KVT + nf*16 + lr) * HC + lg*8;
      bf16x8 k0 = *(const bf16x8*)kp;
      bf16x8 k1 = *(const bf16x8*)(kp + 32);
      s[nf] = __builtin_amdgcn_mfma_f32_16x16x32_bf16(qf0, k0, s[nf], 0, 0, 0);
      s[nf] = __builtin_amdgcn_mfma_f32_16x16x32_bf16(qf1, k1, s[nf], 0, 0, 0);
    }
    // ---- online softmax (rows live across 16 lanes of each group) ----
#pragma unroll
    for (int r = 0; r < 4; r++) {
      float mx = fmaxf(fmaxf(s[0][r], s[1][r]), fmaxf(s[2][r], s[3][r]));
#pragma unroll
      for (int d = 1; d < 16; d <<= 1) mx = fmaxf(mx, __shfl_xor(mx, d));
      float nm = fmaxf(rm[r], mx);
      float corr = __expf(rm[r] - nm);
      rm[r] = nm;
      float ls = 0.f;
#pragma unroll
      for (int nf = 0; nf < 4; nf++) {
        float p = __expf(s[nf][r] - nm);
        s[nf][r] = p;
        ls += p;
      }
#pragma unroll
      for (int d = 1; d < 16; d <<= 1) ls += __shfl_xor(ls, d);
      rs[r] = rs[r] * corr + ls;
#pragma unroll
      for (int cf = 0; cf < 4; cf++) o[cf][r] *= corr;
    }
    // ---- P -> LDS (transpose for PV A-operand) ----
#pragma unroll
    for (int nf = 0; nf < 4; nf++)
#pragma unroll
      for (int r = 0; r < 4; r++)
        plds[w][lg*4 + r][nf*16 + lr] = f2bf(s[nf][r]);
    __syncthreads();
    // ---- O += P V ----
#pragma unroll
    for (int kk = 0; kk < 2; kk++) {
      bf16x8 pa = *(const bf16x8*)(&plds[w][lr][kk*32 + lg*8]);
#pragma unroll
      for (int cf = 0; cf < 4; cf++) {
        const u16* vp = vbase + (size_t)(cf*16 + lr) * N_POS + nt*KVT + kk*32 + lg*8;
        bf16x8 vf = *(const bf16x8*)vp;
        o[cf] = __builtin_amdgcn_mfma_f32_16x16x32_bf16(pa, vf, o[cf], 0, 0, 0);
      }
    }
  }

  // ---- normalize + write O_t [B][N][128] (d = h*64 + c) ----
  u16* ob = Ot + ((size_t)b * N_POS + mt*64 + w*16) * (NH*HC) + h*HC;
#pragma unroll
  for (int cf = 0; cf < 4; cf++)
#pragma unroll
    for (int r = 0; r < 4; r++) {
      float v = o[cf][r] / rs[r];
      ob[(size_t)(lg*4 + r) * (NH*HC) + cf*16 + lr] = f2bf(v);
    }
}

// ---------------------------------------------------------------------------
// Kernel 3: out[b][c][n] = sum_d Ot[n][d] * w2t[c][d] + out_b[c] + x[b][c][n]
// ---------------------------------------------------------------------------
__global__ __launch_bounds__(256) void k_out(const u16* __restrict__ Ot,
                                             const u16* __restrict__ w2t,
                                             const float* __restrict__ obias,
                                             const float* __restrict__ x,
                                             float* __restrict__ out) {
  int b = blockIdx.z;   // 4
  int ct = blockIdx.y;  // 4 (64-wide c tiles)
  int nt = blockIdx.x;  // 64
  int w = threadIdx.x >> 6, l = threadIdx.x & 63;
  int lr = l & 15, lg = l >> 4;

  const u16* arow = Ot + ((size_t)b * N_POS + nt*64 + w*16 + lr) * 128 + lg*8;
  const u16* brow = w2t + ((size_t)(ct*64) + lr) * 128 + lg*8;

  f32x4 acc[4] = {};
#pragma unroll
  for (int kk = 0; kk < 4; kk++) {
    bf16x8 a = *(const bf16x8*)(arow + kk*32);
#pragma unroll
    for (int cf = 0; cf < 4; cf++) {
      bf16x8 bf = *(const bf16x8*)(brow + (size_t)cf*16*128 + kk*32);
      acc[cf] = __builtin_amdgcn_mfma_f32_16x16x32_bf16(a, bf, acc[cf], 0, 0, 0);
    }
  }

  int n0 = nt*64 + w*16 + lg*4;
#pragma unroll
  for (int cf = 0; cf < 4; cf++) {
    int c = ct*64 + cf*16 + lr;
    float bias = obias[c];
    const float* xp = x + ((size_t)b * C_IN + c) * N_POS + n0;
    float* op = out + ((size_t)b * C_IN + c) * N_POS + n0;
    f32x4 xv = *(const f32x4*)xp;
    f32x4 rv;
#pragma unroll
    for (int i = 0; i < 4; i++) rv[i] = acc[cf][i] + bias + xv[i];
    *(f32x4*)op = rv;
  }
}

// ---------------------------------------------------------------------------
extern "C" void kernel_launch(void* const* d_in, const int* in_sizes, int n_in,
                              void* d_out, int out_size, void* d_ws, size_t ws_size,
                              hipStream_t stream) {
  const float* x  = (const float*)d_in[0];   // [4,256,64,64]
  const float* ew = (const float*)d_in[1];   // [2,192,256]
  const float* eb = (const float*)d_in[2];   // [2,192]
  const float* ow = (const float*)d_in[3];   // [128,256]
  const float* ob = (const float*)d_in[4];   // [256]
  float* out = (float*)d_out;

  char* ws = (char*)d_ws;
  u16* xt  = (u16*)(ws + 0);          //  8,388,608 B  x_t  [B][N][C]
  u16* wbf = (u16*)(ws + 8388608);    //    196,608 B  embed_w bf16 [384][256]
  u16* w2t = (u16*)(ws + 8585216);    //     65,536 B  out_w^T bf16 [256][128]
  u16* Qt  = (u16*)(ws + 8650752);    //  4,194,304 B  [8][4096][64]
  u16* Kt  = (u16*)(ws + 12845056);   //  4,194,304 B  [8][4096][64]
  u16* Vc  = (u16*)(ws + 17039360);   //  4,194,304 B  [8][64][4096]
  u16* Ot  = (u16*)(ws + 21233664);   //  4,194,304 B  [B][N][128]

  hipLaunchKernelGGL(k_prep_x, dim3(128, 8, 4), dim3(32, 8), 0, stream, x, xt);
  hipLaunchKernelGGL(k_prep_w, dim3(384), dim3(256), 0, stream, ew, ow, wbf, w2t);
  hipLaunchKernelGGL(k_qkv,  dim3(64, 6, 4), dim3(256), 0, stream, xt, wbf, eb, Qt, Kt, Vc);
  hipLaunchKernelGGL(k_attn, dim3(64, 8),    dim3(256), 0, stream, Qt, Kt, Vc, Ot);
  hipLaunchKernelGGL(k_out,  dim3(64, 4, 4), dim3(256), 0, stream, Ot, w2t, ob, x, out);
}